// Round 4
// baseline (210.804 us; speedup 1.0000x reference)
//
#include <hip/hip_runtime.h>
#include <stdint.h>

typedef unsigned short u16t;
typedef unsigned int   u32t;
typedef _Float16       h16;
typedef __attribute__((ext_vector_type(2)))  _Float16 h16x2;
typedef __attribute__((ext_vector_type(8)))  short    short8;
typedef __attribute__((ext_vector_type(16))) float    f32x16;

#if defined(__has_builtin)
#if __has_builtin(__builtin_amdgcn_fdot2)
#define HAVE_DOT2 1
#endif
#endif

__device__ __forceinline__ float dot2h(u32t a, u32t b, float c){
#ifdef HAVE_DOT2
  return __builtin_amdgcn_fdot2(__builtin_bit_cast(h16x2, a),
                                __builtin_bit_cast(h16x2, b), c, false);
#else
  h16x2 ha = __builtin_bit_cast(h16x2, a), hb = __builtin_bit_cast(h16x2, b);
  return c + (float)ha[0]*(float)hb[0] + (float)ha[1]*(float)hb[1];
#endif
}

__device__ __forceinline__ float bf2f(u16t h){
  union { u32t u; float f; } c; c.u = ((u32t)h) << 16; return c.f;
}
// round-half-up f32 pair -> packed bf16 (2 adds + 1 v_perm; ~= RNE, <=0.5 ulp)
__device__ __forceinline__ u32t pk2bf(float a, float b){
  u32t ua = __builtin_bit_cast(u32t, a) + 0x8000u;
  u32t ub = __builtin_bit_cast(u32t, b) + 0x8000u;
  return __builtin_amdgcn_perm(ub, ua, 0x07060302u);
}
__device__ __forceinline__ u32t pk2h(float a, float b){
  h16x2 h = { (h16)a, (h16)b };
  return __builtin_bit_cast(u32t, h);
}

// dtype-generic helpers ----------------------------------------------------
template<bool BF>
__device__ __forceinline__ float ldv(const void* p, size_t i){
  if constexpr (BF) return bf2f(((const u16t*)p)[i]);
  else              return ((const float*)p)[i];
}
template<bool BF>
__device__ __forceinline__ void ld8(const void* p, size_t i, float* v){
  if constexpr (BF){
    uint4 u = *(const uint4*)((const u16t*)p + i);
    const u32t a[4] = {u.x, u.y, u.z, u.w};
#pragma unroll
    for (int d = 0; d < 4; ++d){
      v[2*d]   = bf2f((u16t)(a[d] & 0xffffu));
      v[2*d+1] = bf2f((u16t)(a[d] >> 16));
    }
  } else {
    const float4* q = (const float4*)((const float*)p + i);
    float4 A = q[0], B = q[1];
    v[0]=A.x; v[1]=A.y; v[2]=A.z; v[3]=A.w;
    v[4]=B.x; v[5]=B.y; v[6]=B.z; v[7]=B.w;
  }
}
// 8 elements -> 4 packed bf16 pairs
template<bool BF>
__device__ __forceinline__ void ld8pk(const void* p, size_t i, u32t* dst){
  if constexpr (BF){
    uint4 u = *(const uint4*)((const u16t*)p + i);
    dst[0]=u.x; dst[1]=u.y; dst[2]=u.z; dst[3]=u.w;
  } else {
    const float4* q = (const float4*)((const float*)p + i);
    float4 A = q[0], B = q[1];
    dst[0] = pk2bf(A.x, A.y); dst[1] = pk2bf(A.z, A.w);
    dst[2] = pk2bf(B.x, B.y); dst[3] = pk2bf(B.z, B.w);
  }
}

// inline per-wave dtype probe on x[0:128] (wave-uniform result, no barrier)
__device__ __forceinline__ bool probe_bf(const void* xv){
  const u16t* p = (const u16t*)xv;
  const int lane = threadIdx.x & 63;
  const u16t h0 = p[lane], h1 = p[lane + 64];
  const int e0 = (h0 >> 7) & 0xff, e1 = (h1 >> 7) & 0xff;
  unsigned long long b0 = __ballot(e0 >= 90 && e0 <= 150);
  unsigned long long b1 = __ballot(e1 >= 90 && e1 <= 150);
  return (__popcll(b0) + __popcll(b1)) >= 104;
}

// ---------------------------------------------------------------------------
// P1: conv1 + dw3x3 + BN + StarReLU -> t2[b,c,ij] f32
// grid 256 = (b, c), block 256 = ij
// ---------------------------------------------------------------------------
template<bool BF>
__device__ __forceinline__ void pre12_body(
    const void* x, const void* w, const void* bias,
    const void* dww, const void* dwb,
    const void* bng, const void* bnb, const void* bnm, const void* bnv,
    const void* s1s, const void* s1b, float* t2)
{
  __shared__ float ts[256];
  const int bid = blockIdx.x;
  const int b = bid >> 7, c = bid & 127;
  const int ij = threadIdx.x, i = ij >> 4, j = ij & 15;
  float a0 = ldv<BF>(bias, c);
  const size_t xb = (size_t)b * 65536 + ij;
#pragma unroll 8
  for (int k = 0; k < 256; ++k)
    a0 += ldv<BF>(x, xb + (size_t)k * 256) * ldv<BF>(w, (size_t)c * 256 + k);
  ts[ij] = a0;
  __syncthreads();
  float s = ldv<BF>(dwb, c);
#pragma unroll
  for (int di = 0; di < 3; ++di){
    const int ii = i + di - 1;
    if (ii < 0 || ii > 15) continue;
#pragma unroll
    for (int dj = 0; dj < 3; ++dj){
      const int jj = j + dj - 1;
      if (jj < 0 || jj > 15) continue;
      s += ts[ii * 16 + jj] * ldv<BF>(dww, c * 9 + di * 3 + dj);
    }
  }
  const float v = ldv<BF>(bng, c) * (s - ldv<BF>(bnm, c)) *
                  rsqrtf(ldv<BF>(bnv, c) + 1e-5f) + ldv<BF>(bnb, c);
  const float r = fmaxf(v, 0.0f);
  t2[((size_t)b * 128 + c) * 256 + ij] = ldv<BF>(s1s, 0) * r * r + ldv<BF>(s1b, 0);
}
__global__ __launch_bounds__(256) void k_pre12(
    const void* x, const void* w, const void* bias,
    const void* dww, const void* dwb,
    const void* bng, const void* bnb, const void* bnm, const void* bnv,
    const void* s1s, const void* s1b, float* t2){
  if (probe_bf(x)) pre12_body<true >(x,w,bias,dww,dwb,bng,bnb,bnm,bnv,s1s,s1b,t2);
  else             pre12_body<false>(x,w,bias,dww,dwb,bng,bnb,bnm,bnv,s1s,s1b,t2);
}

// ---------------------------------------------------------------------------
// P3: channel_expand + StarReLU -> wdech[512] uint4 (packed f16 pairs)
// grid 2 = b, block 256 = ij
// ---------------------------------------------------------------------------
template<bool BF>
__device__ __forceinline__ void pre3_body(
    const void* x, const float* t2, const void* cew, const void* ceb,
    const void* s2s, const void* s2b, uint4* wdech)
{
  __shared__ float cs[8][128];
  const int b = blockIdx.x, ij = threadIdx.x;
  {
    // 1024 weights, 256 threads -> 4 each
    for (int t = ij; t < 1024; t += 256) cs[t >> 7][t & 127] = ldv<BF>(cew, t);
  }
  __syncthreads();
  float a[8];
#pragma unroll
  for (int f = 0; f < 8; ++f) a[f] = ldv<BF>(ceb, f);
#pragma unroll 4
  for (int c = 0; c < 128; ++c){
    const float tv = t2[((size_t)b * 128 + c) * 256 + ij];
#pragma unroll
    for (int f = 0; f < 8; ++f) a[f] += tv * cs[f][c];
  }
  const float sc2 = ldv<BF>(s2s, 0), sb2 = ldv<BF>(s2b, 0);
  float o[8];
#pragma unroll
  for (int f = 0; f < 8; ++f){
    const float r = fmaxf(a[f], 0.0f);
    o[f] = sc2 * r * r + sb2;
  }
  wdech[b * 256 + ij] = make_uint4(pk2h(o[0], o[1]), pk2h(o[2], o[3]),
                                   pk2h(o[4], o[5]), pk2h(o[6], o[7]));
}
__global__ __launch_bounds__(256) void k_pre3(
    const void* x, const float* t2, const void* cew, const void* ceb,
    const void* s2s, const void* s2b, uint4* wdech){
  if (probe_bf(x)) pre3_body<true >(x, t2, cew, ceb, s2s, s2b, wdech);
  else             pre3_body<false>(x, t2, cew, ceb, s2s, s2b, wdech);
}

// ---------------------------------------------------------------------------
// PW: W_base -> packed f16 pairs. 65536 rows of 8. grid 256, block 256.
// ---------------------------------------------------------------------------
template<bool BF>
__device__ __forceinline__ void prew_body(const void* wb, uint4* wbh){
  const int t = blockIdx.x * 256 + threadIdx.x;
  float v[8];
  ld8<BF>(wb, (size_t)t * 8, v);
  wbh[t] = make_uint4(pk2h(v[0], v[1]), pk2h(v[2], v[3]),
                      pk2h(v[4], v[5]), pk2h(v[6], v[7]));
}
__global__ __launch_bounds__(256) void k_prew(const void* x, const void* wb, uint4* wbh){
  if (probe_bf(x)) prew_body<true >(wb, wbh);
  else             prew_body<false>(wb, wbh);
}

// ---------------------------------------------------------------------------
// K3: main hyper-GEMM, 32x32x16 MFMA.
// grid (128, 2): gx=(b,i,j-quad), ec = e-chunk of 128.
// block 1024 = 16 waves (4/SIMD); wave w: g = w&3, e-tile-32 = w>>2.
// LDS: Y^T [4 g][64 pq][256 o] bf16, rotation swizzle (granule = (col_g + row)&31),
// 128 KB, 1 block/CU. One barrier total.
// ---------------------------------------------------------------------------
template<bool BF>
__device__ __forceinline__ void main_body(
    const void* y, const uint4* wbh, const uint4* wdech, float* out, u16t* smem)
{
  const int gx  = blockIdx.x;
  const int ec  = blockIdx.y;
  const int b   = gx >> 6;
  const int i   = (gx >> 2) & 15;
  const int j0  = (gx & 3) * 4;
  const int tid = threadIdx.x;

  // ---- stage: 4 y patches -> LDS [g][pq][o] via in-register 8x8 transpose
  {
    const int o_oct = tid & 31;         // o block of 8
    const int p     = (tid >> 5) & 7;   // 0..7
    const int g     = tid >> 8;         // 0..3
    u32t Rp[8][4];
#pragma unroll
    for (int r = 0; r < 8; ++r){
      const size_t idx = (((size_t)(b * 256 + o_oct * 8 + r)) * 128 + (i * 8 + p)) * 128
                       + (j0 + g) * 8;
      ld8pk<BF>(y, idx, Rp[r]);
    }
#pragma unroll
    for (int q = 0; q < 8; ++q){
      const int d = q >> 1, h = q & 1;
      u32t cc[4];
#pragma unroll
      for (int k = 0; k < 4; ++k){
        const u32t lo32 = Rp[2*k][d], hi32 = Rp[2*k+1][d];
        cc[k] = h ? ((lo32 >> 16)     | (hi32 & 0xffff0000u))
                  : ((lo32 & 0xffffu) | (hi32 << 16));
      }
      const int row  = g * 64 + p * 8 + q;
      const int phys = (o_oct + row) & 31;          // 16B-granule rotation
      *(uint4*)(smem + row * 256 + phys * 8) = make_uint4(cc[0], cc[1], cc[2], cc[3]);
    }
  }
  __syncthreads();   // the only barrier

  const int wave = tid >> 6, lane = tid & 63;
  const int g    = wave & 3, et = wave >> 2;
  const int n31  = lane & 31, kh = lane >> 5;
  const int e0   = ec * 128 + et * 32;
  const int e_a  = e0 + n31;                        // A-fragment row (m = lane&31)

  // wdec packed f16 pairs for this wave's g
  u32t wdp[4];
  {
    const uint4 q = wdech[b * 256 + i * 16 + j0 + g];
    wdp[0] = q.x; wdp[1] = q.y; wdp[2] = q.z; wdp[3] = q.w;
  }

  f32x16 acc[2];
#pragma unroll
  for (int nt = 0; nt < 2; ++nt)
#pragma unroll
    for (int k = 0; k < 16; ++k) acc[nt][k] = 0.0f;

  const uint4* wrow = wbh + (size_t)e_a * 256 + kh * 8;

#pragma unroll
  for (int ks = 0; ks < 16; ++ks){
    // A-gen: lane's 8 o-values (o = ks*16 + kh*8 + r) for e = e_a
    uint4 Wq[8];
#pragma unroll
    for (int r = 0; r < 8; ++r) Wq[r] = wrow[ks * 16 + r];
    float s[8];
#pragma unroll
    for (int r = 0; r < 8; ++r){
      float t = dot2h(Wq[r].x, wdp[0], 0.0f);
      t = dot2h(Wq[r].y, wdp[1], t);
      t = dot2h(Wq[r].z, wdp[2], t);
      s[r] = dot2h(Wq[r].w, wdp[3], t);
    }
    u32t a4[4];
#pragma unroll
    for (int d = 0; d < 4; ++d) a4[d] = pk2bf(s[2*d], s[2*d+1]);
    const short8 af = __builtin_bit_cast(short8, *(uint4*)a4);
#pragma unroll
    for (int nt = 0; nt < 2; ++nt){
      const int rowf = g * 64 + nt * 32 + n31;      // B n-row
      const int phys = (2 * ks + kh + rowf) & 31;   // same rotation as write
      const short8 bfr = *(const short8*)(smem + rowf * 256 + phys * 8);
      acc[nt] = __builtin_amdgcn_mfma_f32_32x32x16_bf16(af, bfr, acc[nt], 0, 0, 0);
    }
  }

  // ---- epilogue: 32x32 C/D layout col=lane&31, row=(r&3)+8*(r>>2)+4*(lane>>5)
#pragma unroll
  for (int nt = 0; nt < 2; ++nt){
    const int pq = nt * 32 + n31;
    const int pp = pq >> 3, qq = pq & 7;
    const size_t obase = ((size_t)(b * 256) * 128 + (i * 8 + pp)) * 128
                       + (j0 + g) * 8 + qq;
#pragma unroll
    for (int r = 0; r < 16; ++r){
      const int ee = e0 + (r & 3) + 8 * (r >> 2) + 4 * kh;
      out[obase + (size_t)ee * 16384] = acc[nt][r];
    }
  }
}
__global__ __launch_bounds__(1024, 4) void k_main(
    const void* x, const void* y, const uint4* wbh, const uint4* wdech, float* out){
  extern __shared__ __align__(16) u16t smem[];
  if (probe_bf(x)) main_body<true >(y, wbh, wdech, out, smem);
  else             main_body<false>(y, wbh, wdech, out, smem);
}

// ---------------------------------------------------------------------------
extern "C" void kernel_launch(void* const* d_in, const int* in_sizes, int n_in,
                              void* d_out, int out_size, void* d_ws, size_t ws_size,
                              hipStream_t stream)
{
  float* t2    = (float*)d_ws;                       // 262144 B
  uint4* wdech = (uint4*)((char*)d_ws + 262144);     // 8192 B
  uint4* wbh   = (uint4*)((char*)d_ws + 270336);     // 1048576 B

  k_pre12<<<dim3(256), dim3(256), 0, stream>>>(
      d_in[0], d_in[2], d_in[3], d_in[4], d_in[5], d_in[6], d_in[7],
      d_in[8], d_in[9], d_in[10], d_in[11], t2);
  k_pre3<<<dim3(2), dim3(256), 0, stream>>>(
      d_in[0], t2, d_in[12], d_in[13], d_in[14], d_in[15], wdech);
  k_prew<<<dim3(256), dim3(256), 0, stream>>>(d_in[0], d_in[16], wbh);

  const int lds_bytes = 4 * 64 * 256 * 2;            // 131072
  hipFuncSetAttribute((const void*)k_main,
                      hipFuncAttributeMaxDynamicSharedMemorySize, lds_bytes);
  k_main<<<dim3(128, 2), dim3(1024), lds_bytes, stream>>>(
      d_in[0], d_in[1], wbh, wdech, (float*)d_out);
}

// Round 5
// 173.620 us; speedup vs baseline: 1.2142x; 1.2142x over previous
//
#include <hip/hip_runtime.h>
#include <stdint.h>

typedef unsigned short u16t;
typedef unsigned int   u32t;
typedef _Float16       h16;
typedef __attribute__((ext_vector_type(2))) _Float16 h16x2;
typedef __attribute__((ext_vector_type(8))) short    short8;
typedef __attribute__((ext_vector_type(4))) float    f32x4;

#if defined(__has_builtin)
#if __has_builtin(__builtin_amdgcn_fdot2)
#define HAVE_DOT2 1
#endif
#endif

__device__ __forceinline__ float dot2h(u32t a, u32t b, float c){
#ifdef HAVE_DOT2
  return __builtin_amdgcn_fdot2(__builtin_bit_cast(h16x2, a),
                                __builtin_bit_cast(h16x2, b), c, false);
#else
  h16x2 ha = __builtin_bit_cast(h16x2, a), hb = __builtin_bit_cast(h16x2, b);
  return c + (float)ha[0]*(float)hb[0] + (float)ha[1]*(float)hb[1];
#endif
}

__device__ __forceinline__ float bf2f(u16t h){
  union { u32t u; float f; } c; c.u = ((u32t)h) << 16; return c.f;
}
// round-half-up f32 pair -> packed bf16 (2 adds + 1 v_perm) [HW-verified r4]
__device__ __forceinline__ u32t pk2bf(float a, float b){
  u32t ua = __builtin_bit_cast(u32t, a) + 0x8000u;
  u32t ub = __builtin_bit_cast(u32t, b) + 0x8000u;
  return __builtin_amdgcn_perm(ub, ua, 0x07060302u);
}
__device__ __forceinline__ u32t pk2h(float a, float b){
  h16x2 h = { (h16)a, (h16)b };
  return __builtin_bit_cast(u32t, h);
}

// dtype-generic helpers ----------------------------------------------------
template<bool BF>
__device__ __forceinline__ float ldv(const void* p, size_t i){
  if constexpr (BF) return bf2f(((const u16t*)p)[i]);
  else              return ((const float*)p)[i];
}
template<bool BF>
__device__ __forceinline__ void ld8(const void* p, size_t i, float* v){
  if constexpr (BF){
    uint4 u = *(const uint4*)((const u16t*)p + i);
    const u32t a[4] = {u.x, u.y, u.z, u.w};
#pragma unroll
    for (int d = 0; d < 4; ++d){
      v[2*d]   = bf2f((u16t)(a[d] & 0xffffu));
      v[2*d+1] = bf2f((u16t)(a[d] >> 16));
    }
  } else {
    const float4* q = (const float4*)((const float*)p + i);
    float4 A = q[0], B = q[1];
    v[0]=A.x; v[1]=A.y; v[2]=A.z; v[3]=A.w;
    v[4]=B.x; v[5]=B.y; v[6]=B.z; v[7]=B.w;
  }
}
// 8 elements -> 4 packed bf16 pairs
template<bool BF>
__device__ __forceinline__ void ld8pk(const void* p, size_t i, u32t* dst){
  if constexpr (BF){
    uint4 u = *(const uint4*)((const u16t*)p + i);
    dst[0]=u.x; dst[1]=u.y; dst[2]=u.z; dst[3]=u.w;
  } else {
    const float4* q = (const float4*)((const float*)p + i);
    float4 A = q[0], B = q[1];
    dst[0] = pk2bf(A.x, A.y); dst[1] = pk2bf(A.z, A.w);
    dst[2] = pk2bf(B.x, B.y); dst[3] = pk2bf(B.z, B.w);
  }
}

// inline per-wave dtype probe on x[0:128] (wave-uniform, no barrier)
__device__ __forceinline__ bool probe_bf(const void* xv){
  const u16t* p = (const u16t*)xv;
  const int lane = threadIdx.x & 63;
  const u16t h0 = p[lane], h1 = p[lane + 64];
  const int e0 = (h0 >> 7) & 0xff, e1 = (h1 >> 7) & 0xff;
  unsigned long long b0 = __ballot(e0 >= 90 && e0 <= 150);
  unsigned long long b1 = __ballot(e1 >= 90 && e1 <= 150);
  return (__popcll(b0) + __popcll(b1)) >= 104;
}

// ---------------------------------------------------------------------------
// P1: conv1 + dw3x3 + BN + StarReLU -> t2[b,c,ij] f32. grid 256=(b,c), blk 256
// ---------------------------------------------------------------------------
template<bool BF>
__device__ __forceinline__ void pre12_body(
    const void* x, const void* w, const void* bias,
    const void* dww, const void* dwb,
    const void* bng, const void* bnb, const void* bnm, const void* bnv,
    const void* s1s, const void* s1b, float* t2)
{
  __shared__ float ts[256];
  const int bid = blockIdx.x;
  const int b = bid >> 7, c = bid & 127;
  const int ij = threadIdx.x, i = ij >> 4, j = ij & 15;
  float a0 = ldv<BF>(bias, c);
  const size_t xb = (size_t)b * 65536 + ij;
#pragma unroll 8
  for (int k = 0; k < 256; ++k)
    a0 += ldv<BF>(x, xb + (size_t)k * 256) * ldv<BF>(w, (size_t)c * 256 + k);
  ts[ij] = a0;
  __syncthreads();
  float s = ldv<BF>(dwb, c);
#pragma unroll
  for (int di = 0; di < 3; ++di){
    const int ii = i + di - 1;
    if (ii < 0 || ii > 15) continue;
#pragma unroll
    for (int dj = 0; dj < 3; ++dj){
      const int jj = j + dj - 1;
      if (jj < 0 || jj > 15) continue;
      s += ts[ii * 16 + jj] * ldv<BF>(dww, c * 9 + di * 3 + dj);
    }
  }
  const float v = ldv<BF>(bng, c) * (s - ldv<BF>(bnm, c)) *
                  rsqrtf(ldv<BF>(bnv, c) + 1e-5f) + ldv<BF>(bnb, c);
  const float r = fmaxf(v, 0.0f);
  t2[((size_t)b * 128 + c) * 256 + ij] = ldv<BF>(s1s, 0) * r * r + ldv<BF>(s1b, 0);
}
__global__ __launch_bounds__(256) void k_pre12(
    const void* x, const void* w, const void* bias,
    const void* dww, const void* dwb,
    const void* bng, const void* bnb, const void* bnm, const void* bnv,
    const void* s1s, const void* s1b, float* t2){
  if (probe_bf(x)) pre12_body<true >(x,w,bias,dww,dwb,bng,bnb,bnm,bnv,s1s,s1b,t2);
  else             pre12_body<false>(x,w,bias,dww,dwb,bng,bnb,bnm,bnv,s1s,s1b,t2);
}

// ---------------------------------------------------------------------------
// P3: channel_expand + StarReLU -> wdech[512] uint4 (packed f16 pairs)
// ---------------------------------------------------------------------------
template<bool BF>
__device__ __forceinline__ void pre3_body(
    const void* x, const float* t2, const void* cew, const void* ceb,
    const void* s2s, const void* s2b, uint4* wdech)
{
  __shared__ float cs[8][128];
  const int b = blockIdx.x, ij = threadIdx.x;
  for (int t = ij; t < 1024; t += 256) cs[t >> 7][t & 127] = ldv<BF>(cew, t);
  __syncthreads();
  float a[8];
#pragma unroll
  for (int f = 0; f < 8; ++f) a[f] = ldv<BF>(ceb, f);
#pragma unroll 4
  for (int c = 0; c < 128; ++c){
    const float tv = t2[((size_t)b * 128 + c) * 256 + ij];
#pragma unroll
    for (int f = 0; f < 8; ++f) a[f] += tv * cs[f][c];
  }
  const float sc2 = ldv<BF>(s2s, 0), sb2 = ldv<BF>(s2b, 0);
  float o[8];
#pragma unroll
  for (int f = 0; f < 8; ++f){
    const float r = fmaxf(a[f], 0.0f);
    o[f] = sc2 * r * r + sb2;
  }
  wdech[b * 256 + ij] = make_uint4(pk2h(o[0], o[1]), pk2h(o[2], o[3]),
                                   pk2h(o[4], o[5]), pk2h(o[6], o[7]));
}
__global__ __launch_bounds__(256) void k_pre3(
    const void* x, const float* t2, const void* cew, const void* ceb,
    const void* s2s, const void* s2b, uint4* wdech){
  if (probe_bf(x)) pre3_body<true >(x, t2, cew, ceb, s2s, s2b, wdech);
  else             pre3_body<false>(x, t2, cew, ceb, s2s, s2b, wdech);
}

// ---------------------------------------------------------------------------
// PW: W_base -> permuted packed-f16 layout wbh2[o][e] (uint4 granules).
// wbh2[o*256 + e] = f16x8 of W_base[(e*256+o)*8 .. +8).
// K-loop reads instruction (ks,kq,r): lanes l15 -> 16 consecutive uint4 = 256 B.
// grid 256, block 256; t = bid*256+tid; e = t&255 (coalesced dst), o = t>>8.
// ---------------------------------------------------------------------------
template<bool BF>
__device__ __forceinline__ void prew_body(const void* wb, uint4* wbh2){
  const int t = blockIdx.x * 256 + threadIdx.x;
  const int e = t & 255, o = t >> 8;
  float v[8];
  ld8<BF>(wb, ((size_t)e * 256 + o) * 8, v);
  wbh2[(size_t)o * 256 + e] = make_uint4(pk2h(v[0], v[1]), pk2h(v[2], v[3]),
                                         pk2h(v[4], v[5]), pk2h(v[6], v[7]));
}
__global__ __launch_bounds__(256) void k_prew(const void* x, const void* wb, uint4* wbh2){
  if (probe_bf(x)) prew_body<true >(wb, wbh2);
  else             prew_body<false>(wb, wbh2);
}

// ---------------------------------------------------------------------------
// K3: main hyper-GEMM, 16x16x32 MFMA, W double-buffered from permuted layout.
// grid 512 (1D, XCD-swizzled): ec = (bid>>3)&1, gx = (bid&7)|((bid>>4)<<3);
// gx = (b, i, j-pair). block 512 = 8 waves; wave = e-tile of 16 (e-chunk 128).
// LDS: Y^T [2 g][64 pq][256 o] bf16, 16B-granule rotation, 64 KB -> 2 blk/CU.
// One barrier total.
// ---------------------------------------------------------------------------
template<bool BF>
__device__ __forceinline__ void main_body(
    const void* y, const uint4* wbh2, const uint4* wdech, float* out, u16t* smem)
{
  const int bid = blockIdx.x;
  const int ec  = (bid >> 3) & 1;
  const int gx  = (bid & 7) | ((bid >> 4) << 3);
  const int b   = gx >> 7;
  const int i   = (gx >> 3) & 15;
  const int j0  = (gx & 7) * 2;
  const int tid = threadIdx.x;

  // ---- stage: 2 y patches -> LDS [g][pq][o] via in-register 8x8 transpose
  {
    const int o_oct = tid & 31;         // o granule of 8
    const int p     = (tid >> 5) & 7;
    const int g     = tid >> 8;         // 0..1
    u32t Rp[8][4];
#pragma unroll
    for (int r = 0; r < 8; ++r){
      const size_t idx = (((size_t)(b * 256 + o_oct * 8 + r)) * 128 + (i * 8 + p)) * 128
                       + (j0 + g) * 8;
      ld8pk<BF>(y, idx, Rp[r]);
    }
#pragma unroll
    for (int q = 0; q < 8; ++q){
      const int d = q >> 1, h = q & 1;
      u32t cc[4];
#pragma unroll
      for (int k = 0; k < 4; ++k){
        const u32t lo32 = Rp[2*k][d], hi32 = Rp[2*k+1][d];
        cc[k] = h ? ((lo32 >> 16)     | (hi32 & 0xffff0000u))
                  : ((lo32 & 0xffffu) | (hi32 << 16));
      }
      const int row  = g * 64 + p * 8 + q;
      const int phys = (o_oct + row) & 31;          // rotation swizzle
      *(uint4*)(smem + row * 256 + phys * 8) = make_uint4(cc[0], cc[1], cc[2], cc[3]);
    }
  }

  const int wave = tid >> 6, lane = tid & 63;
  const int l15 = lane & 15, l4 = lane >> 4;
  const int e0  = ec * 128 + wave * 16;

  // wdec packed f16 pairs for both g
  u32t wdp[2][4];
#pragma unroll
  for (int g = 0; g < 2; ++g){
    const uint4 q = wdech[b * 256 + i * 16 + j0 + g];
    wdp[g][0] = q.x; wdp[g][1] = q.y; wdp[g][2] = q.z; wdp[g][3] = q.w;
  }

  // W loads: o = ks*32 + l4*8 + r ; idx = o*256 + e0 + l15 (coalesced in l15)
  const uint4* wrow = wbh2 + (size_t)(l4 * 8) * 256 + e0 + l15;

  uint4 Wb[2][8];
#pragma unroll
  for (int r = 0; r < 8; ++r) Wb[0][r] = wrow[(size_t)r * 256];

  f32x4 acc[2][4];
#pragma unroll
  for (int g = 0; g < 2; ++g)
#pragma unroll
    for (int nt = 0; nt < 4; ++nt)
      acc[g][nt] = (f32x4){0.f, 0.f, 0.f, 0.f};

  __syncthreads();   // the only barrier

#pragma unroll
  for (int ks = 0; ks < 8; ++ks){
    const int cur = ks & 1;
    if (ks < 7){
#pragma unroll
      for (int r = 0; r < 8; ++r)
        Wb[cur ^ 1][r] = wrow[(size_t)((ks + 1) * 32 + r) * 256];
    }
    // A-gen: s[g][r] = dot(W[e, o=ks*32+l4*8+r][:], wdec_g)
    float s[2][8];
#pragma unroll
    for (int r = 0; r < 8; ++r){
      const uint4 w4 = Wb[cur][r];
#pragma unroll
      for (int g = 0; g < 2; ++g){
        float t = dot2h(w4.x, wdp[g][0], 0.0f);
        t = dot2h(w4.y, wdp[g][1], t);
        t = dot2h(w4.z, wdp[g][2], t);
        s[g][r] = dot2h(w4.w, wdp[g][3], t);
      }
    }
#pragma unroll
    for (int g = 0; g < 2; ++g){
      u32t a4[4];
#pragma unroll
      for (int d = 0; d < 4; ++d) a4[d] = pk2bf(s[g][2*d], s[g][2*d+1]);
      const short8 af = __builtin_bit_cast(short8, *(uint4*)a4);
#pragma unroll
      for (int nt = 0; nt < 4; ++nt){
        const int row  = g * 64 + nt * 16 + l15;
        const int phys = (ks * 4 + l4 + row) & 31;
        const short8 bfr = *(const short8*)(smem + row * 256 + phys * 8);
        acc[g][nt] = __builtin_amdgcn_mfma_f32_16x16x32_bf16(af, bfr, acc[g][nt], 0, 0, 0);
      }
    }
  }

  // ---- epilogue: C/D layout col=lane&15, row=(lane>>4)*4+reg
#pragma unroll
  for (int g = 0; g < 2; ++g){
#pragma unroll
    for (int nt = 0; nt < 4; ++nt){
      const int col = nt * 16 + l15;
      const int pp = col >> 3, qq = col & 7;
#pragma unroll
      for (int r = 0; r < 4; ++r){
        const int ee = e0 + l4 * 4 + r;
        const size_t oaddr = ((size_t)(b * 256 + ee) * 128 + (i * 8 + pp)) * 128
                           + (j0 + g) * 8 + qq;
        out[oaddr] = acc[g][nt][r];
      }
    }
  }
}
__global__ __launch_bounds__(512, 4) void k_main(
    const void* x, const void* y, const uint4* wbh2, const uint4* wdech, float* out){
  extern __shared__ __align__(16) u16t smem[];
  if (probe_bf(x)) main_body<true >(y, wbh2, wdech, out, smem);
  else             main_body<false>(y, wbh2, wdech, out, smem);
}

// ---------------------------------------------------------------------------
extern "C" void kernel_launch(void* const* d_in, const int* in_sizes, int n_in,
                              void* d_out, int out_size, void* d_ws, size_t ws_size,
                              hipStream_t stream)
{
  float* t2    = (float*)d_ws;                       // 262144 B
  uint4* wdech = (uint4*)((char*)d_ws + 262144);     // 8192 B
  uint4* wbh2  = (uint4*)((char*)d_ws + 270336);     // 1048576 B

  k_pre12<<<dim3(256), dim3(256), 0, stream>>>(
      d_in[0], d_in[2], d_in[3], d_in[4], d_in[5], d_in[6], d_in[7],
      d_in[8], d_in[9], d_in[10], d_in[11], t2);
  k_pre3<<<dim3(2), dim3(256), 0, stream>>>(
      d_in[0], t2, d_in[12], d_in[13], d_in[14], d_in[15], wdech);
  k_prew<<<dim3(256), dim3(256), 0, stream>>>(d_in[0], d_in[16], wbh2);

  const int lds_bytes = 2 * 64 * 256 * 2;            // 65536
  hipFuncSetAttribute((const void*)k_main,
                      hipFuncAttributeMaxDynamicSharedMemorySize, lds_bytes);
  k_main<<<dim3(512), dim3(512), lds_bytes, stream>>>(
      d_in[0], d_in[1], wbh2, wdech, (float*)d_out);
}